// Round 2
// baseline (117.703 us; speedup 1.0000x reference)
//
#include <hip/hip_runtime.h>
#include <hip/hip_bf16.h>

#define VOCAB 100000
#define EMBED 64
#define NPAIR (1024 * 50)   // B*S
#define KIDS  20

// ---------------------------------------------------------------------------
// Kernel 1: transpose W [E=64, V] (row-major) -> Wt [V, E=64] (row-major).
// LDS-tiled 64x64 transpose; coalesced reads along v, contiguous float4 writes.
// ---------------------------------------------------------------------------
__global__ __launch_bounds__(256) void transpose_w(const float* __restrict__ W,
                                                   float* __restrict__ Wt) {
    __shared__ float tile[64][65];   // +1 pad: bank-conflict-free
    const int v0 = blockIdx.x * 64;
    const int tx = threadIdx.x & 63;   // v offset within tile
    const int ty = threadIdx.x >> 6;   // 0..3
    const int v = v0 + tx;
    if (v < VOCAB) {
        #pragma unroll
        for (int e = ty; e < 64; e += 4) {
            tile[tx][e] = W[(size_t)e * VOCAB + v];
        }
    }
    __syncthreads();
    // Each thread writes 16 contiguous floats of Wt (4 x float4).
    const int r  = threadIdx.x >> 2;          // v offset within tile
    const int c0 = (threadIdx.x & 3) * 16;    // e base
    if (v0 + r < VOCAB) {
        float4* outv = (float4*)(Wt + (size_t)(v0 + r) * 64 + c0);
        #pragma unroll
        for (int i = 0; i < 4; i++) {
            outv[i] = make_float4(tile[r][c0 + 4 * i + 0],
                                  tile[r][c0 + 4 * i + 1],
                                  tile[r][c0 + 4 * i + 2],
                                  tile[r][c0 + 4 * i + 3]);
        }
    }
}

// ---------------------------------------------------------------------------
// Kernel 2: gather-reduce. One wave (64 lanes) per (b,s) pair; lane = embed e.
// Each gather Wt[id*64 + lane] is one coalesced 256B wave transaction.
// ---------------------------------------------------------------------------
__global__ __launch_bounds__(256) void gather_t(const int* __restrict__ ids,
                                                const float* __restrict__ Wt,
                                                const float* __restrict__ bias,
                                                float* __restrict__ out) {
    const int wave = (blockIdx.x * blockDim.x + threadIdx.x) >> 6;
    const int lane = threadIdx.x & 63;
    if (wave >= NPAIR) return;

    // 20 ids = 5 x int4, 16B-aligned (wave*80 bytes).
    const int4* idv = (const int4*)(ids + (size_t)wave * KIDS);
    int4 q0 = idv[0], q1 = idv[1], q2 = idv[2], q3 = idv[3], q4 = idv[4];

    float acc = bias[lane];
    acc += Wt[(size_t)q0.x * 64 + lane];
    acc += Wt[(size_t)q0.y * 64 + lane];
    acc += Wt[(size_t)q0.z * 64 + lane];
    acc += Wt[(size_t)q0.w * 64 + lane];
    acc += Wt[(size_t)q1.x * 64 + lane];
    acc += Wt[(size_t)q1.y * 64 + lane];
    acc += Wt[(size_t)q1.z * 64 + lane];
    acc += Wt[(size_t)q1.w * 64 + lane];
    acc += Wt[(size_t)q2.x * 64 + lane];
    acc += Wt[(size_t)q2.y * 64 + lane];
    acc += Wt[(size_t)q2.z * 64 + lane];
    acc += Wt[(size_t)q2.w * 64 + lane];
    acc += Wt[(size_t)q3.x * 64 + lane];
    acc += Wt[(size_t)q3.y * 64 + lane];
    acc += Wt[(size_t)q3.z * 64 + lane];
    acc += Wt[(size_t)q3.w * 64 + lane];
    acc += Wt[(size_t)q4.x * 64 + lane];
    acc += Wt[(size_t)q4.y * 64 + lane];
    acc += Wt[(size_t)q4.z * 64 + lane];
    acc += Wt[(size_t)q4.w * 64 + lane];

    out[(size_t)wave * 64 + lane] = acc;
}

// ---------------------------------------------------------------------------
// Fallback (ws too small): direct uncoalesced gather on native W [E, V].
// ---------------------------------------------------------------------------
__global__ __launch_bounds__(256) void gather_direct(const int* __restrict__ ids,
                                                     const float* __restrict__ W,
                                                     const float* __restrict__ bias,
                                                     float* __restrict__ out) {
    const int wave = (blockIdx.x * blockDim.x + threadIdx.x) >> 6;
    const int lane = threadIdx.x & 63;
    if (wave >= NPAIR) return;

    const int* myids = ids + (size_t)wave * KIDS;
    float acc = bias[lane];
    #pragma unroll
    for (int k = 0; k < KIDS; k++) {
        int id = myids[k];
        acc += W[(size_t)lane * VOCAB + id];
    }
    out[(size_t)wave * 64 + lane] = acc;
}

extern "C" void kernel_launch(void* const* d_in, const int* in_sizes, int n_in,
                              void* d_out, int out_size, void* d_ws, size_t ws_size,
                              hipStream_t stream) {
    const int*   ids  = (const int*)d_in[0];    // [B,S,K] int32
    const float* W    = (const float*)d_in[1];  // [E, V] fp32
    const float* bias = (const float*)d_in[2];  // [E] fp32
    float*       out  = (float*)d_out;          // [B,S,E] fp32

    const size_t wt_bytes = (size_t)VOCAB * EMBED * sizeof(float);

    if (ws_size >= wt_bytes) {
        float* Wt = (float*)d_ws;
        const int tr_blocks = (VOCAB + 63) / 64;           // 1563
        transpose_w<<<tr_blocks, 256, 0, stream>>>(W, Wt);
        const int g_blocks = (NPAIR * 64 + 255) / 256;     // 12800
        gather_t<<<g_blocks, 256, 0, stream>>>(ids, Wt, bias, out);
    } else {
        const int g_blocks = (NPAIR * 64 + 255) / 256;
        gather_direct<<<g_blocks, 256, 0, stream>>>(ids, W, bias, out);
    }
}

// Round 3
// 96.836 us; speedup vs baseline: 1.2155x; 1.2155x over previous
//
#include <hip/hip_runtime.h>
#include <hip/hip_bf16.h>

#define VOCAB 100000
#define EMBED 64
#define NPAIR (1024 * 50)   // B*S
#define KIDS  20

static __device__ inline ushort f2bf(float f) {
    __hip_bfloat16 h = __float2bfloat16(f);   // RN conversion
    return __builtin_bit_cast(ushort, h);
}
static __device__ inline float bf2f(ushort u) {
    unsigned int v = ((unsigned int)u) << 16;  // exact widening
    return __builtin_bit_cast(float, v);
}

// ---------------------------------------------------------------------------
// Kernel 1: transpose+convert W [E=64, V] fp32 -> Wt [V, E=64] bf16 (12.8 MB).
// LDS-tiled; coalesced reads along v, packed 16B bf16 writes.
// ---------------------------------------------------------------------------
__global__ __launch_bounds__(256) void convert_w(const float* __restrict__ W,
                                                 ushort* __restrict__ Wt) {
    __shared__ float tile[64][65];   // +1 pad
    const int v0 = blockIdx.x * 64;
    const int tx = threadIdx.x & 63;   // v offset within tile
    const int ty = threadIdx.x >> 6;   // 0..3
    const int v = v0 + tx;
    if (v < VOCAB) {
        #pragma unroll
        for (int e = ty; e < 64; e += 4) {
            tile[tx][e] = W[(size_t)e * VOCAB + v];
        }
    }
    __syncthreads();
    // Each thread packs 16 bf16 (32 B) of one Wt row.
    const int r  = threadIdx.x >> 2;          // v offset within tile (0..63... wait 256/4=64) 
    const int c0 = (threadIdx.x & 3) * 16;    // e base
    if (v0 + r < VOCAB) {
        uint pk[8];
        #pragma unroll
        for (int i = 0; i < 8; i++) {
            ushort lo = f2bf(tile[r][c0 + 2 * i + 0]);
            ushort hi = f2bf(tile[r][c0 + 2 * i + 1]);
            pk[i] = (uint)lo | ((uint)hi << 16);
        }
        uint4* outv = (uint4*)(Wt + (size_t)(v0 + r) * 64 + c0);
        outv[0] = make_uint4(pk[0], pk[1], pk[2], pk[3]);
        outv[1] = make_uint4(pk[4], pk[5], pk[6], pk[7]);
    }
}

// ---------------------------------------------------------------------------
// Kernel 2: gather-reduce on bf16 table. One wave per (b,s); lane = embed e.
// Each gather = one coalesced 128 B wave transaction (2 x 64B lines).
// ---------------------------------------------------------------------------
__global__ __launch_bounds__(256) void gather_bf16(const int* __restrict__ ids,
                                                   const ushort* __restrict__ Wt,
                                                   const float* __restrict__ bias,
                                                   float* __restrict__ out) {
    const int wave = (blockIdx.x * blockDim.x + threadIdx.x) >> 6;
    const int lane = threadIdx.x & 63;
    if (wave >= NPAIR) return;

    // 20 ids = 5 x int4, 16B-aligned (wave*80 bytes).
    const int4* idv = (const int4*)(ids + (size_t)wave * KIDS);
    int4 q0 = idv[0], q1 = idv[1], q2 = idv[2], q3 = idv[3], q4 = idv[4];

    // 32-bit offsets: id*64 + lane fits easily in 32 bits.
    ushort r0  = Wt[((uint)q0.x << 6) + lane];
    ushort r1  = Wt[((uint)q0.y << 6) + lane];
    ushort r2  = Wt[((uint)q0.z << 6) + lane];
    ushort r3  = Wt[((uint)q0.w << 6) + lane];
    ushort r4  = Wt[((uint)q1.x << 6) + lane];
    ushort r5  = Wt[((uint)q1.y << 6) + lane];
    ushort r6  = Wt[((uint)q1.z << 6) + lane];
    ushort r7  = Wt[((uint)q1.w << 6) + lane];
    ushort r8  = Wt[((uint)q2.x << 6) + lane];
    ushort r9  = Wt[((uint)q2.y << 6) + lane];
    ushort r10 = Wt[((uint)q2.z << 6) + lane];
    ushort r11 = Wt[((uint)q2.w << 6) + lane];
    ushort r12 = Wt[((uint)q3.x << 6) + lane];
    ushort r13 = Wt[((uint)q3.y << 6) + lane];
    ushort r14 = Wt[((uint)q3.z << 6) + lane];
    ushort r15 = Wt[((uint)q3.w << 6) + lane];
    ushort r16 = Wt[((uint)q4.x << 6) + lane];
    ushort r17 = Wt[((uint)q4.y << 6) + lane];
    ushort r18 = Wt[((uint)q4.z << 6) + lane];
    ushort r19 = Wt[((uint)q4.w << 6) + lane];

    float acc = bias[lane];
    acc += bf2f(r0);  acc += bf2f(r1);  acc += bf2f(r2);  acc += bf2f(r3);
    acc += bf2f(r4);  acc += bf2f(r5);  acc += bf2f(r6);  acc += bf2f(r7);
    acc += bf2f(r8);  acc += bf2f(r9);  acc += bf2f(r10); acc += bf2f(r11);
    acc += bf2f(r12); acc += bf2f(r13); acc += bf2f(r14); acc += bf2f(r15);
    acc += bf2f(r16); acc += bf2f(r17); acc += bf2f(r18); acc += bf2f(r19);

    // Non-temporal: don't let the 13 MB output stream evict Wt from L2.
    __builtin_nontemporal_store(acc, &out[(size_t)wave * 64 + lane]);
}

// ---------------------------------------------------------------------------
// Fallback (ws too small): direct uncoalesced gather on native W [E, V].
// ---------------------------------------------------------------------------
__global__ __launch_bounds__(256) void gather_direct(const int* __restrict__ ids,
                                                     const float* __restrict__ W,
                                                     const float* __restrict__ bias,
                                                     float* __restrict__ out) {
    const int wave = (blockIdx.x * blockDim.x + threadIdx.x) >> 6;
    const int lane = threadIdx.x & 63;
    if (wave >= NPAIR) return;

    const int* myids = ids + (size_t)wave * KIDS;
    float acc = bias[lane];
    #pragma unroll
    for (int k = 0; k < KIDS; k++) {
        int id = myids[k];
        acc += W[(size_t)lane * VOCAB + id];
    }
    out[(size_t)wave * 64 + lane] = acc;
}

extern "C" void kernel_launch(void* const* d_in, const int* in_sizes, int n_in,
                              void* d_out, int out_size, void* d_ws, size_t ws_size,
                              hipStream_t stream) {
    const int*   ids  = (const int*)d_in[0];    // [B,S,K] int32
    const float* W    = (const float*)d_in[1];  // [E, V] fp32
    const float* bias = (const float*)d_in[2];  // [E] fp32
    float*       out  = (float*)d_out;          // [B,S,E] fp32

    const size_t wt_bytes = (size_t)VOCAB * EMBED * sizeof(ushort);  // 12.8 MB

    if (ws_size >= wt_bytes) {
        ushort* Wt = (ushort*)d_ws;
        const int tr_blocks = (VOCAB + 63) / 64;           // 1563
        convert_w<<<tr_blocks, 256, 0, stream>>>(W, Wt);
        const int g_blocks = (NPAIR * 64 + 255) / 256;     // 12800
        gather_bf16<<<g_blocks, 256, 0, stream>>>(ids, Wt, bias, out);
    } else {
        const int g_blocks = (NPAIR * 64 + 255) / 256;
        gather_direct<<<g_blocks, 256, 0, stream>>>(ids, W, bias, out);
    }
}